// Round 15
// baseline (174.444 us; speedup 1.0000x reference)
//
#include <hip/hip_runtime.h>

#define N_PTS  20000
#define NG     128                  // grid NG x NG over [-6,6]^2
#define NC     (NG * NG)            // 16384 cells per cloud
#define GMIN   (-6.0f)
#define GINV   (NG / 12.0f)
#define MARGIN 5e-4f                // >> 2e-5 worst-case |P_np - d_true^2|
#define NWAVE  4096                 // persistent waves in k_main (1024 blocks)
#define QB79   79                   // fallback

// ---- numpy-exact helpers (proven rounds 2/5/9/10/11/14) ----
__device__ __forceinline__ float np_self_dot(float x, float y, float z) {
    return __fadd_rn(__fadd_rn(__fmul_rn(x, x), __fmul_rn(y, y)),
                     __fmul_rn(z, z));
}
__device__ __forceinline__ unsigned ordmap(float f) {
    unsigned b = __float_as_uint(f);
    return (b & 0x80000000u) ? ~b : (b | 0x80000000u);
}
__device__ __forceinline__ float invord(unsigned h) {
    return __uint_as_float((h & 0x80000000u) ? (h ^ 0x80000000u) : ~h);
}
__device__ __forceinline__ int cellC(float v) {
    int c = (int)((v - GMIN) * GINV);
    return c < 0 ? 0 : (c > NG - 1 ? NG - 1 : c);
}
__device__ __forceinline__ unsigned long long wave_min_u64(unsigned long long k) {
    #pragma unroll
    for (int m = 1; m < 64; m <<= 1) {
        unsigned long long o = __shfl_xor(k, m, 64);
        k = (o < k) ? o : k;
    }
    return k;
}

// ---- build A: LDS-only hist+scan (1 block/cloud) -> bstart + global cursor
__global__ __launch_bounds__(1024) void k_histscan(
    const float* __restrict__ preds, const float* __restrict__ gts,
    int* __restrict__ bstart, int* __restrict__ cursor)
{
    __shared__ int hist[NC];        // 64 KB
    __shared__ int psum[1024];      // 4 KB
    int cl = blockIdx.x, t = threadIdx.x;
    const float* src = cl ? gts : preds;

    for (int i = t; i < NC; i += 1024) hist[i] = 0;
    __syncthreads();
    for (int i = t; i < N_PTS; i += 1024) {
        int cell = cellC(src[i*3+0]) * NG + cellC(src[i*3+1]);
        atomicAdd(&hist[cell], 1);
    }
    __syncthreads();

    int base = t * 16;
    int v[16], s = 0;
    #pragma unroll
    for (int i = 0; i < 16; ++i) { v[i] = hist[base + i]; s += v[i]; }
    psum[t] = s;
    __syncthreads();
    for (int off = 1; off < 1024; off <<= 1) {     // Hillis-Steele inclusive
        int a = (t >= off) ? psum[t - off] : 0;
        __syncthreads();
        psum[t] += a;
        __syncthreads();
    }
    int run = psum[t] - s;                          // exclusive prefix
    #pragma unroll
    for (int i = 0; i < 16; ++i) {
        bstart[cl * (NC + 1) + base + i] = run;
        cursor[cl * NC + base + i] = run;
        run += v[i];
    }
    if (t == 1023) bstart[cl * (NC + 1) + NC] = run;   // == N_PTS
}

// ---- build B: wide scatter (157 blocks) into cell-sorted order ----
// Record = {x, y, z, bitcast(orig_idx)} (r14's proven layout).
__global__ __launch_bounds__(256) void k_scatter(
    const float* __restrict__ preds, const float* __restrict__ gts,
    int* __restrict__ cursor, float4* __restrict__ sorted)
{
    int t = blockIdx.x * 256 + threadIdx.x;
    if (t >= 2 * N_PTS) return;
    int cl = t / N_PTS, i = t - cl * N_PTS;
    const float* src = cl ? gts : preds;
    float x = src[i*3+0], y = src[i*3+1], z = src[i*3+2];
    int cell = cellC(x) * NG + cellC(y);
    int pos = atomicAdd(&cursor[cl * NC + cell], 1);
    sorted[(size_t)cl * N_PTS + pos] = make_float4(x, y, z, __int_as_float(i));
}

// ---- main: PERSISTENT wave-per-query. 1024 long-lived blocks (4/CU,
// 16 waves/CU sustained) each wave strides queries by NWAVE — removes the
// workgroup-dispatch-rate bottleneck behind r11/r14's 22% occupancy and
// interleaves heavy/light queries. Per-query machinery bit-identical to
// r11/r14 (passed): numpy-exact P; key=(ordmap(P)<<32|idx); wave-min ==
// numpy first-occurrence argmin; per-axis prune with MARGIN strict-safe.
__global__ __launch_bounds__(256) void k_main(
    const float4* __restrict__ sorted, const int* __restrict__ bstart,
    float* __restrict__ out)
{
    int gw   = blockIdx.x * 4 + ((int)threadIdx.x >> 6);   // 0..NWAVE-1
    int lane = threadIdx.x & 63;

    for (int wid = gw; wid < 2 * N_PTS; wid += NWAVE) {
        int dir  = wid / N_PTS;
        int qpos = wid - dir * N_PTS;
        int rcl  = 1 - dir;

        const float4* rs = sorted + (size_t)rcl * N_PTS;
        const int*    cs = bstart + rcl * (NC + 1);

        float4 qv    = sorted[(size_t)dir * N_PTS + qpos];   // wave-broadcast
        int    origq = __float_as_int(qv.w);
        float qx = qv.x, qy = qv.y, qz = qv.z;
        float sq = np_self_dot(qx, qy, qz);

        unsigned long long key = ~0ULL;

#define EVAL(p)                                                            \
    {   float4 r = rs[p];                                                  \
        float sr = np_self_dot(r.x, r.y, r.z);                             \
        float zz = __fadd_rn(__fadd_rn(__fmul_rn(qx, r.x),                 \
                                       __fmul_rn(qy, r.y)),                \
                             __fmul_rn(qz, r.z));                          \
        float P  = __fsub_rn(__fadd_rn(sq, sr), __fadd_rn(zz, zz));        \
        unsigned long long kk =                                            \
            ((unsigned long long)ordmap(P) << 32) | __float_as_uint(r.w);  \
        key = (kk < key) ? kk : key; }

#define ROW(x, ya, yb)                                                     \
    if ((yb) >= (ya)) {                                                    \
        int lo = cs[(x) * NG + (ya)], hi = cs[(x) * NG + (yb) + 1];        \
        for (int p = lo + lane; p < hi; p += 64) EVAL(p)                   \
    }

        int cx = cellC(qx), cy = cellC(qy);
        int sxL = cx > 0 ? cx - 1 : 0, sxR = cx < NG-1 ? cx + 1 : NG-1;
        int syL = cy > 0 ? cy - 1 : 0, syR = cy < NG-1 ? cy + 1 : NG-1;

        for (int x = sxL; x <= sxR; ++x) ROW(x, syL, syR)    // seed 3x3

        for (int round = 0; round < 24; ++round) {
            key = wave_min_u64(key);
            int txL, txR, tyL, tyR;
            if (key != ~0ULL) {
                float W = sqrtf(invord((unsigned)(key >> 32)) + MARGIN);
                txL = cellC(qx - W); txR = cellC(qx + W);
                tyL = cellC(qy - W); tyR = cellC(qy + W);
            } else {                                         // empty: grow
                int gx = sxR - sxL + 1, gy = syR - syL + 1;
                txL = sxL - gx; txR = sxR + gx;
                tyL = syL - gy; tyR = syR + gy;
                txL = txL < 0 ? 0 : txL;  tyL = tyL < 0 ? 0 : tyL;
                txR = txR > NG-1 ? NG-1 : txR;
                tyR = tyR > NG-1 ? NG-1 : tyR;
            }
            if (txL >= sxL && txR <= sxR && tyL >= syL && tyR <= syR) break;
            for (int x = txL; x <= txR; ++x) {
                if (x >= sxL && x <= sxR) {                  // new strips only
                    ROW(x, tyL, syL - 1)
                    ROW(x, syR + 1, tyR)
                } else {
                    ROW(x, tyL, tyR)
                }
            }
            sxL = txL; sxR = txR; syL = tyL; syR = tyR;
        }
#undef ROW
#undef EVAL

        key = wave_min_u64(key);
        if (lane == 0) {
            out[dir * N_PTS + origq]       = invord((unsigned)(key >> 32));
            out[(2 + dir) * N_PTS + origq] = (float)(unsigned)(key & 0xFFFFFFFFu);
        }
    }
}

// ---- fallback (tiny workspace): brute-force direct kernel (proven r2) ----
__device__ __forceinline__ float np_pair(float sq, float sr,
                                         float qx, float qy, float qz,
                                         float rx, float ry, float rz) {
    float zz = __fadd_rn(__fadd_rn(__fmul_rn(qx, rx), __fmul_rn(qy, ry)),
                         __fmul_rn(qz, rz));
    return __fsub_rn(__fadd_rn(sq, sr), __fadd_rn(zz, zz));
}

__global__ __launch_bounds__(256) void chamfer_direct_kernel(
    const float* __restrict__ preds, const float* __restrict__ gts,
    float* __restrict__ out)
{
    __shared__ float4 spts[256];
    int bid = blockIdx.x;
    int dir = bid / QB79;
    int qb  = bid - dir * QB79;
    int q   = qb * 256 + threadIdx.x;

    const float* qpts = (dir == 0) ? preds : gts;
    const float* rpts = (dir == 0) ? gts   : preds;

    int qc = (q < N_PTS) ? q : (N_PTS - 1);
    float qx = qpts[qc*3+0], qy = qpts[qc*3+1], qz = qpts[qc*3+2];
    float sq = np_self_dot(qx, qy, qz);
    float best = 3.4e38f;
    int   bidx = 0;

    for (int t = 0; t < N_PTS; t += 256) {
        int cnt = min(256, N_PTS - t);
        __syncthreads();
        if ((int)threadIdx.x < cnt) {
            int j = t + threadIdx.x;
            float rx = rpts[j*3+0], ry = rpts[j*3+1], rz = rpts[j*3+2];
            spts[threadIdx.x] = make_float4(rx, ry, rz, np_self_dot(rx, ry, rz));
        }
        __syncthreads();
        for (int k = 0; k < cnt; ++k) {
            float4 r = spts[k];
            float d = np_pair(sq, r.w, qx, qy, qz, r.x, r.y, r.z);
            if (d < best) { best = d; bidx = t + k; }
        }
    }
    if (q < N_PTS) {
        out[dir * N_PTS + q]       = best;
        out[(2 + dir) * N_PTS + q] = (float)bidx;
    }
}

extern "C" void kernel_launch(void* const* d_in, const int* in_sizes, int n_in,
                              void* d_out, int out_size, void* d_ws, size_t ws_size,
                              hipStream_t stream) {
    const float* preds = (const float*)d_in[0];  // [20000, 3]
    const float* gts   = (const float*)d_in[1];  // [1, 20000, 3]
    float* out = (float*)d_out;

    char* w = (char*)d_ws;
    size_t sorted_b = (size_t)2 * N_PTS * sizeof(float4);   // 640000
    size_t bstart_b = (size_t)2 * (NC + 1) * sizeof(int);   // 131080
    size_t cursor_b = (size_t)2 * NC * sizeof(int);         // 131072
    size_t need = sorted_b + bstart_b + cursor_b;

    if (ws_size >= need) {
        float4* sorted = (float4*)w;
        int* bstart = (int*)(w + sorted_b);
        int* cursor = (int*)(w + sorted_b + bstart_b);

        k_histscan<<<2, 1024, 0, stream>>>(preds, gts, bstart, cursor);
        k_scatter<<<(2 * N_PTS + 255) / 256, 256, 0, stream>>>(
            preds, gts, cursor, sorted);
        k_main<<<NWAVE / 4, 256, 0, stream>>>(sorted, bstart, out);
    } else {
        chamfer_direct_kernel<<<2 * QB79, 256, 0, stream>>>(preds, gts, out);
    }
}

// Round 16
// 148.603 us; speedup vs baseline: 1.1739x; 1.1739x over previous
//
#include <hip/hip_runtime.h>

#define N_PTS  20000
#define NG     128                  // grid NG x NG over [-6,6]^2
#define NC     (NG * NG)            // 16384 cells per cloud
#define GMIN   (-6.0f)
#define GINV   (NG / 12.0f)
#define MARGIN 5e-4f                // >> 2e-5 worst-case |P_np - d_true^2|
#define QB79   79                   // fallback

// ---- numpy-exact helpers (proven rounds 2/5/9/10/11/14) ----
__device__ __forceinline__ float np_self_dot(float x, float y, float z) {
    return __fadd_rn(__fadd_rn(__fmul_rn(x, x), __fmul_rn(y, y)),
                     __fmul_rn(z, z));
}
__device__ __forceinline__ unsigned ordmap(float f) {
    unsigned b = __float_as_uint(f);
    return (b & 0x80000000u) ? ~b : (b | 0x80000000u);
}
__device__ __forceinline__ float invord(unsigned h) {
    return __uint_as_float((h & 0x80000000u) ? (h ^ 0x80000000u) : ~h);
}
__device__ __forceinline__ int cellC(float v) {
    int c = (int)((v - GMIN) * GINV);
    return c < 0 ? 0 : (c > NG - 1 ? NG - 1 : c);
}
__device__ __forceinline__ unsigned long long wave_min_u64(unsigned long long k) {
    #pragma unroll
    for (int m = 1; m < 64; m <<= 1) {
        unsigned long long o = __shfl_xor(k, m, 64);
        k = (o < k) ? o : k;
    }
    return k;
}

// ---- build A (r15, measured fast): LDS-only hist+scan, 1 block/cloud ----
__global__ __launch_bounds__(1024) void k_histscan(
    const float* __restrict__ preds, const float* __restrict__ gts,
    int* __restrict__ bstart, int* __restrict__ cursor)
{
    __shared__ int hist[NC];        // 64 KB
    __shared__ int psum[1024];      // 4 KB
    int cl = blockIdx.x, t = threadIdx.x;
    const float* src = cl ? gts : preds;

    for (int i = t; i < NC; i += 1024) hist[i] = 0;
    __syncthreads();
    for (int i = t; i < N_PTS; i += 1024) {
        int cell = cellC(src[i*3+0]) * NG + cellC(src[i*3+1]);
        atomicAdd(&hist[cell], 1);
    }
    __syncthreads();

    int base = t * 16;
    int v[16], s = 0;
    #pragma unroll
    for (int i = 0; i < 16; ++i) { v[i] = hist[base + i]; s += v[i]; }
    psum[t] = s;
    __syncthreads();
    for (int off = 1; off < 1024; off <<= 1) {     // Hillis-Steele inclusive
        int a = (t >= off) ? psum[t - off] : 0;
        __syncthreads();
        psum[t] += a;
        __syncthreads();
    }
    int run = psum[t] - s;                          // exclusive prefix
    #pragma unroll
    for (int i = 0; i < 16; ++i) {
        bstart[cl * (NC + 1) + base + i] = run;
        cursor[cl * NC + base + i] = run;
        run += v[i];
    }
    if (t == 1023) bstart[cl * (NC + 1) + NC] = run;   // == N_PTS
}

// ---- build B (r15): wide scatter (157 blocks) into cell-sorted order ----
// Record = {x, y, z, bitcast(orig_idx)} (r14's proven layout).
__global__ __launch_bounds__(256) void k_scatter(
    const float* __restrict__ preds, const float* __restrict__ gts,
    int* __restrict__ cursor, float4* __restrict__ sorted)
{
    int t = blockIdx.x * 256 + threadIdx.x;
    if (t >= 2 * N_PTS) return;
    int cl = t / N_PTS, i = t - cl * N_PTS;
    const float* src = cl ? gts : preds;
    float x = src[i*3+0], y = src[i*3+1], z = src[i*3+2];
    int cell = cellC(x) * NG + cellC(y);
    int pos = atomicAdd(&cursor[cl * NC + cell], 1);
    sorted[(size_t)cl * N_PTS + pos] = make_float4(x, y, z, __int_as_float(i));
}

// ---- main: r14's 10000-block wave-per-query (87us, passed; persistent
// variant regressed — r15 post-mortem) + 2-way unrolled gather for MLP.
// Min is commutative; rescans idempotent => unroll/coverage order safe.
// Numerics bit-identical to r9-r15: numpy-exact P; key=(ordmap(P)<<32|idx);
// wave-min == numpy first-occurrence argmin; MARGIN-pruning strict-safe.
__global__ __launch_bounds__(256) void k_main(
    const float4* __restrict__ sorted, const int* __restrict__ bstart,
    float* __restrict__ out)
{
    int wid  = blockIdx.x * 4 + ((int)threadIdx.x >> 6);   // 0..39999
    int lane = threadIdx.x & 63;
    int dir  = wid / N_PTS;
    int qpos = wid - dir * N_PTS;
    int rcl  = 1 - dir;

    const float4* rs = sorted + (size_t)rcl * N_PTS;
    const int*    cs = bstart + rcl * (NC + 1);

    float4 qv    = sorted[(size_t)dir * N_PTS + qpos];     // wave-broadcast
    int    origq = __float_as_int(qv.w);
    float qx = qv.x, qy = qv.y, qz = qv.z;
    float sq = np_self_dot(qx, qy, qz);

    unsigned long long key = ~0ULL;

#define EVAL(r)                                                            \
    {   float sr = np_self_dot((r).x, (r).y, (r).z);                       \
        float zz = __fadd_rn(__fadd_rn(__fmul_rn(qx, (r).x),               \
                                       __fmul_rn(qy, (r).y)),              \
                             __fmul_rn(qz, (r).z));                        \
        float P  = __fsub_rn(__fadd_rn(sq, sr), __fadd_rn(zz, zz));        \
        unsigned long long kk =                                            \
            ((unsigned long long)ordmap(P) << 32) | __float_as_uint((r).w);\
        key = (kk < key) ? kk : key; }

#define ROW(x, ya, yb)                                                     \
    if ((yb) >= (ya)) {                                                    \
        int lo = cs[(x) * NG + (ya)], hi = cs[(x) * NG + (yb) + 1];        \
        int p = lo + lane;                                                 \
        for (; p + 64 < hi; p += 128) {                                    \
            float4 r0 = rs[p];                                             \
            float4 r1 = rs[p + 64];        /* 2 loads in flight */         \
            EVAL(r0) EVAL(r1)                                              \
        }                                                                  \
        if (p < hi) { float4 r0 = rs[p]; EVAL(r0) }                        \
    }

    int cx = cellC(qx), cy = cellC(qy);
    int sxL = cx > 0 ? cx - 1 : 0, sxR = cx < NG-1 ? cx + 1 : NG-1;
    int syL = cy > 0 ? cy - 1 : 0, syR = cy < NG-1 ? cy + 1 : NG-1;

    for (int x = sxL; x <= sxR; ++x) ROW(x, syL, syR)      // seed 3x3

    for (int round = 0; round < 24; ++round) {
        key = wave_min_u64(key);
        int txL, txR, tyL, tyR;
        if (key != ~0ULL) {
            float W = sqrtf(invord((unsigned)(key >> 32)) + MARGIN);
            txL = cellC(qx - W); txR = cellC(qx + W);
            tyL = cellC(qy - W); tyR = cellC(qy + W);
        } else {                                           // empty seed: grow
            int gx = sxR - sxL + 1, gy = syR - syL + 1;
            txL = sxL - gx; txR = sxR + gx;
            tyL = syL - gy; tyR = syR + gy;
            txL = txL < 0 ? 0 : txL;  tyL = tyL < 0 ? 0 : tyL;
            txR = txR > NG-1 ? NG-1 : txR;
            tyR = tyR > NG-1 ? NG-1 : tyR;
        }
        if (txL >= sxL && txR <= sxR && tyL >= syL && tyR <= syR) break;
        for (int x = txL; x <= txR; ++x) {
            if (x >= sxL && x <= sxR) {                    // new strips only
                ROW(x, tyL, syL - 1)
                ROW(x, syR + 1, tyR)
            } else {
                ROW(x, tyL, tyR)
            }
        }
        sxL = txL; sxR = txR; syL = tyL; syR = tyR;
    }
#undef ROW
#undef EVAL

    key = wave_min_u64(key);
    if (lane == 0) {
        out[dir * N_PTS + origq]       = invord((unsigned)(key >> 32));
        out[(2 + dir) * N_PTS + origq] = (float)(unsigned)(key & 0xFFFFFFFFu);
    }
}

// ---- fallback (tiny workspace): brute-force direct kernel (proven r2) ----
__device__ __forceinline__ float np_pair(float sq, float sr,
                                         float qx, float qy, float qz,
                                         float rx, float ry, float rz) {
    float zz = __fadd_rn(__fadd_rn(__fmul_rn(qx, rx), __fmul_rn(qy, ry)),
                         __fmul_rn(qz, rz));
    return __fsub_rn(__fadd_rn(sq, sr), __fadd_rn(zz, zz));
}

__global__ __launch_bounds__(256) void chamfer_direct_kernel(
    const float* __restrict__ preds, const float* __restrict__ gts,
    float* __restrict__ out)
{
    __shared__ float4 spts[256];
    int bid = blockIdx.x;
    int dir = bid / QB79;
    int qb  = bid - dir * QB79;
    int q   = qb * 256 + threadIdx.x;

    const float* qpts = (dir == 0) ? preds : gts;
    const float* rpts = (dir == 0) ? gts   : preds;

    int qc = (q < N_PTS) ? q : (N_PTS - 1);
    float qx = qpts[qc*3+0], qy = qpts[qc*3+1], qz = qpts[qc*3+2];
    float sq = np_self_dot(qx, qy, qz);
    float best = 3.4e38f;
    int   bidx = 0;

    for (int t = 0; t < N_PTS; t += 256) {
        int cnt = min(256, N_PTS - t);
        __syncthreads();
        if ((int)threadIdx.x < cnt) {
            int j = t + threadIdx.x;
            float rx = rpts[j*3+0], ry = rpts[j*3+1], rz = rpts[j*3+2];
            spts[threadIdx.x] = make_float4(rx, ry, rz, np_self_dot(rx, ry, rz));
        }
        __syncthreads();
        for (int k = 0; k < cnt; ++k) {
            float4 r = spts[k];
            float d = np_pair(sq, r.w, qx, qy, qz, r.x, r.y, r.z);
            if (d < best) { best = d; bidx = t + k; }
        }
    }
    if (q < N_PTS) {
        out[dir * N_PTS + q]       = best;
        out[(2 + dir) * N_PTS + q] = (float)bidx;
    }
}

extern "C" void kernel_launch(void* const* d_in, const int* in_sizes, int n_in,
                              void* d_out, int out_size, void* d_ws, size_t ws_size,
                              hipStream_t stream) {
    const float* preds = (const float*)d_in[0];  // [20000, 3]
    const float* gts   = (const float*)d_in[1];  // [1, 20000, 3]
    float* out = (float*)d_out;

    char* w = (char*)d_ws;
    size_t sorted_b = (size_t)2 * N_PTS * sizeof(float4);   // 640000
    size_t bstart_b = (size_t)2 * (NC + 1) * sizeof(int);   // 131080
    size_t cursor_b = (size_t)2 * NC * sizeof(int);         // 131072
    size_t need = sorted_b + bstart_b + cursor_b;

    if (ws_size >= need) {
        float4* sorted = (float4*)w;
        int* bstart = (int*)(w + sorted_b);
        int* cursor = (int*)(w + sorted_b + bstart_b);

        k_histscan<<<2, 1024, 0, stream>>>(preds, gts, bstart, cursor);
        k_scatter<<<(2 * N_PTS + 255) / 256, 256, 0, stream>>>(
            preds, gts, cursor, sorted);
        k_main<<<2 * N_PTS / 4, 256, 0, stream>>>(sorted, bstart, out);
    } else {
        chamfer_direct_kernel<<<2 * QB79, 256, 0, stream>>>(preds, gts, out);
    }
}